// Round 1
// baseline (689.660 us; speedup 1.0000x reference)
//
#include <hip/hip_runtime.h>
#include <math.h>

// R3: fully fused, ZERO-workspace kernel.
//
// R2 used d_ws for seg[] + sd[] precompute; the harness re-poisons the 2 GB
// workspace arena every timed iteration (fillBufferAligned, 2.147 GB @ ~330 us
// each — the entire top-5 of the rocprof table). The precompute it paid for is
// worth ~10 us. R3 drops d_ws entirely:
//   - seg lookup: rows in a block are 32 contiguous; only 1023 boundaries in
//     1M rows -> ~97% of blocks are single-segment. Two threads binary-search
//     the block's first/last row (ptr = 4 KB, L1-hot), broadcast [s0,s1] via
//     LDS; each row then linearly advances (expected ~0.03 steps).
//   - sd = summary*d*scale precompute replaced by in-flight d[h] multiply
//     (L1-hot) and scale at the epilogue — free against a memory-bound loop.
// Memory: emb 512 MB streamed + out 4 MB => roofline ~85 us @ 6.3 TB/s.

#define HDIM 128
#define NEPS 1e-12f
#define ROWS_PER_BLOCK 32   // 256 threads, 8 lanes per row

__global__ __launch_bounds__(256) void sim_fused(
    const float* __restrict__ emb,
    const float* __restrict__ summary,
    const int*   __restrict__ ptr,
    const float* __restrict__ dvec,
    const float* __restrict__ scale,
    float* __restrict__ out, int N, int B)
{
    __shared__ int s_bounds[2];

    const long long row0 = (long long)blockIdx.x * ROWS_PER_BLOCK;

    // threads 0/1: binary-search segment of first/last row of this block.
    // seg(i) = searchsorted(ptr[1:], i, right) = count of ptr[1..B] <= i.
    if (threadIdx.x < 2) {
        long long r = row0 + (threadIdx.x ? ROWS_PER_BLOCK - 1 : 0);
        if (r > (long long)N - 1) r = (long long)N - 1;
        int lo = 0, hi = B;
        while (lo < hi) {
            int mid = (lo + hi) >> 1;
            if (ptr[1 + mid] <= (int)r) lo = mid + 1; else hi = mid;
        }
        s_bounds[threadIdx.x] = lo;
    }
    __syncthreads();
    const int s0 = s_bounds[0];
    const int s1 = s_bounds[1];

    const int sub = threadIdx.x & 7;                        // lane in 8-lane row group
    const long long row = row0 + (threadIdx.x >> 3);
    if (row >= N) return;

    // narrow per-row segment: invariant ptr[s] <= row; advance while next
    // boundary is still <= row. Uniform across the 8-lane group, L1-hit loads.
    int s = s0;
    while (s < s1 && ptr[s + 1] <= (int)row) ++s;

    const float4* e4 = (const float4*)(emb + row * (long long)HDIM);
    const float4* w4 = (const float4*)(summary + (long long)s * HDIM);
    const float4* d4 = (const float4*)dvec;

    float sumsq = 0.f, dot = 0.f;
    #pragma unroll
    for (int j = 0; j < 4; ++j) {
        const float4 e  = e4[sub + 8 * j];
        const float4 w  = w4[sub + 8 * j];
        const float4 dd = d4[sub + 8 * j];
        sumsq = fmaf(e.x, e.x, sumsq); sumsq = fmaf(e.y, e.y, sumsq);
        sumsq = fmaf(e.z, e.z, sumsq); sumsq = fmaf(e.w, e.w, sumsq);
        dot = fmaf(e.x, w.x * dd.x, dot); dot = fmaf(e.y, w.y * dd.y, dot);
        dot = fmaf(e.z, w.z * dd.z, dot); dot = fmaf(e.w, w.w * dd.w, dot);
    }
    // reduce across the 8-lane group (xor masks 4,2,1 stay in-group)
    #pragma unroll
    for (int m = 4; m >= 1; m >>= 1) {
        sumsq += __shfl_xor(sumsq, m, 64);
        dot   += __shfl_xor(dot,   m, 64);
    }
    if (sub == 0)
        out[row] = dot / fmaxf(sqrtf(sumsq), NEPS) * scale[0];
}

extern "C" void kernel_launch(void* const* d_in, const int* in_sizes, int n_in,
                              void* d_out, int out_size, void* d_ws, size_t ws_size,
                              hipStream_t stream) {
    const float* emb     = (const float*)d_in[0];
    const float* summary = (const float*)d_in[1];
    const int*   ptr     = (const int*)d_in[2];
    const float* dvec    = (const float*)d_in[3];
    const float* scale   = (const float*)d_in[4];
    float*       out     = (float*)d_out;

    const int Hn = in_sizes[3];           // 128
    const int N  = in_sizes[0] / Hn;      // 1048576
    const int B  = in_sizes[1] / Hn;      // 1024

    (void)d_ws; (void)ws_size; (void)n_in; (void)out_size;

    sim_fused<<<(N + ROWS_PER_BLOCK - 1) / ROWS_PER_BLOCK, 256, 0, stream>>>(
        emb, summary, ptr, dvec, scale, out, N, B);
}

// Round 2
// 680.514 us; speedup vs baseline: 1.0134x; 1.0134x over previous
//
#include <hip/hip_runtime.h>
#include <math.h>

// R4: discriminating experiment — maximize ILP / minimize per-row overhead.
//
// Evidence so far: ws-poison fill (2.147 GB, ~334 us) is UNCONDITIONAL (still
// present with zero-ws R3); dur_us was invariant (679->690) under removal of 2
// dispatches + 4.5 MB of scratch traffic => dur_us = harness floor (~600 us)
// + kernel (<333 us, invisible below the fill wall in top-5).
// This round: 4 rows/thread (4 independent load chains, 4x MLP), 128-row
// blocks (search amortized 4x), block-uniform fast path hoisting w*d into
// registers (~87% of blocks; halves VMEM instr count in the hot loop).
// If dur_us doesn't move, kernel is already at its ~60-90 us roofline and the
// rest is harness floor.

#define HDIM 128
#define NEPS 1e-12f
#define ROWS_PER_ITER 32     // 256 threads / 8 lanes per row
#define ITERS 4
#define ROWS_PER_BLOCK 128   // ROWS_PER_ITER * ITERS

__global__ __launch_bounds__(256) void sim_fused(
    const float* __restrict__ emb,
    const float* __restrict__ summary,
    const int*   __restrict__ ptr,
    const float* __restrict__ dvec,
    const float* __restrict__ scale,
    float* __restrict__ out, int N, int B)
{
    __shared__ int s_bounds[2];

    const long long row0 = (long long)blockIdx.x * ROWS_PER_BLOCK;

    // threads 0/1: binary-search segment of first/last row of this block.
    // seg(i) = count of ptr[1..B] <= i  (searchsorted(ptr[1:], i, 'right')).
    if (threadIdx.x < 2) {
        long long r = row0 + (threadIdx.x ? ROWS_PER_BLOCK - 1 : 0);
        if (r > (long long)N - 1) r = (long long)N - 1;
        int lo = 0, hi = B;
        while (lo < hi) {
            int mid = (lo + hi) >> 1;
            if (ptr[1 + mid] <= (int)r) lo = mid + 1; else hi = mid;
        }
        s_bounds[threadIdx.x] = lo;
    }
    __syncthreads();
    const int s0 = s_bounds[0];
    const int s1 = s_bounds[1];

    const int sub = threadIdx.x & 7;         // lane within 8-lane row group
    const int grp = threadIdx.x >> 3;        // row group 0..31
    const float sc = scale[0];
    const float4* d4 = (const float4*)dvec;

    if (s0 == s1) {
        // ---- fast path (~87% of blocks): whole block in one segment ----
        const float4* w4 = (const float4*)(summary + (long long)s0 * HDIM);
        float4 wd[4];
        #pragma unroll
        for (int j = 0; j < 4; ++j) {
            const float4 w  = w4[sub + 8 * j];
            const float4 dd = d4[sub + 8 * j];
            wd[j] = make_float4(w.x * dd.x, w.y * dd.y, w.z * dd.z, w.w * dd.w);
        }
        #pragma unroll
        for (int it = 0; it < ITERS; ++it) {
            const long long row = row0 + it * ROWS_PER_ITER + grp;
            if (row >= N) break;
            const float4* e4 = (const float4*)(emb + row * (long long)HDIM);
            float sumsq = 0.f, dot = 0.f;
            #pragma unroll
            for (int j = 0; j < 4; ++j) {
                const float4 e = e4[sub + 8 * j];
                sumsq = fmaf(e.x, e.x, sumsq); sumsq = fmaf(e.y, e.y, sumsq);
                sumsq = fmaf(e.z, e.z, sumsq); sumsq = fmaf(e.w, e.w, sumsq);
                dot = fmaf(e.x, wd[j].x, dot); dot = fmaf(e.y, wd[j].y, dot);
                dot = fmaf(e.z, wd[j].z, dot); dot = fmaf(e.w, wd[j].w, dot);
            }
            #pragma unroll
            for (int m = 4; m >= 1; m >>= 1) {
                sumsq += __shfl_xor(sumsq, m, 64);
                dot   += __shfl_xor(dot,   m, 64);
            }
            if (sub == 0)
                out[row] = dot / fmaxf(sqrtf(sumsq), NEPS) * sc;
        }
    } else {
        // ---- slow path: block spans >=1 boundary; per-row linear advance ----
        int s = s0;  // invariant: ptr[s] <= current row (rows ascend with it)
        #pragma unroll
        for (int it = 0; it < ITERS; ++it) {
            const long long row = row0 + it * ROWS_PER_ITER + grp;
            if (row >= N) break;
            while (s < s1 && ptr[s + 1] <= (int)row) ++s;
            const float4* e4 = (const float4*)(emb + row * (long long)HDIM);
            const float4* w4 = (const float4*)(summary + (long long)s * HDIM);
            float sumsq = 0.f, dot = 0.f;
            #pragma unroll
            for (int j = 0; j < 4; ++j) {
                const float4 e  = e4[sub + 8 * j];
                const float4 w  = w4[sub + 8 * j];
                const float4 dd = d4[sub + 8 * j];
                sumsq = fmaf(e.x, e.x, sumsq); sumsq = fmaf(e.y, e.y, sumsq);
                sumsq = fmaf(e.z, e.z, sumsq); sumsq = fmaf(e.w, e.w, sumsq);
                dot = fmaf(e.x, w.x * dd.x, dot); dot = fmaf(e.y, w.y * dd.y, dot);
                dot = fmaf(e.z, w.z * dd.z, dot); dot = fmaf(e.w, w.w * dd.w, dot);
            }
            #pragma unroll
            for (int m = 4; m >= 1; m >>= 1) {
                sumsq += __shfl_xor(sumsq, m, 64);
                dot   += __shfl_xor(dot,   m, 64);
            }
            if (sub == 0)
                out[row] = dot / fmaxf(sqrtf(sumsq), NEPS) * sc;
        }
    }
}

extern "C" void kernel_launch(void* const* d_in, const int* in_sizes, int n_in,
                              void* d_out, int out_size, void* d_ws, size_t ws_size,
                              hipStream_t stream) {
    const float* emb     = (const float*)d_in[0];
    const float* summary = (const float*)d_in[1];
    const int*   ptr     = (const int*)d_in[2];
    const float* dvec    = (const float*)d_in[3];
    const float* scale   = (const float*)d_in[4];
    float*       out     = (float*)d_out;

    const int Hn = in_sizes[3];           // 128
    const int N  = in_sizes[0] / Hn;      // 1048576
    const int B  = in_sizes[1] / Hn;      // 1024

    (void)d_ws; (void)ws_size; (void)n_in; (void)out_size;

    sim_fused<<<(N + ROWS_PER_BLOCK - 1) / ROWS_PER_BLOCK, 256, 0, stream>>>(
        emb, summary, ptr, dvec, scale, out, N, B);
}